// Round 13
// baseline (184.965 us; speedup 1.0000x reference)
//
#include <hip/hip_runtime.h>

// FactorizedSpectralConv: B=8, S1=S2=256, C=64, M1=M2=32.
// Fused per-dim kernels: truncated DFT (MFMA f16) -> complex mix (MFMA f16)
// -> iDFT (MFMA f16) -> direct fragment stores.
//
// R13 = R11 (canonical pw layout, lane-contiguous k2 stores, launch_bounds
// (512,2)) + R12's validated prefetch timing, now with scalar f16 loads at
// canonical addresses:
//   pf0 (h=0) issued after phase-2 barrier  -> hidden under phase 3
//   pf1 (h=1) issued after phase-3 barrier  -> hidden under bf4 + h=0 work
// R12 lesson: producer stores must stay lane-contiguous; the interleaved pw
// layout gave 2x sector write-amp + 2x k2 time. Consumer-side latency is
// handled by prefetch, not layout.
//
// MFMA mapping discipline: logical k index f(g2,e) = 8*g2 + e used for BOTH
// A (init-built tables) and B (LDS staging layout). C/D layout:
// col = lane&31, row = (reg&3) + 8*(reg>>2) + 4*(lane>>5)  [HW-verified].
// Lessons: R3-R5 write-amp was register spills (keep VGPR budget >= need).

namespace {

constexpr int S = 256, C = 64;

typedef _Float16 f16;
typedef _Float16 f16x2 __attribute__((ext_vector_type(2)));
typedef _Float16 f16x4 __attribute__((ext_vector_type(4)));
typedef _Float16 f16x8 __attribute__((ext_vector_type(8)));
typedef float f32x16 __attribute__((ext_vector_type(16)));

// ws layout (float offsets)
constexpr int OFF_FWDF = 0;       // fwd A-frag table: 16384 f16 (8192 fl)
constexpr int OFF_INVF = 8192;    // inv A-frag table: 16384 f16 (8192 fl)
constexpr int OFF_A2   = 16384;   // mix A-frag tables: 2 dims x 524288 f16
constexpr int OFF_PW   = 540672;  // f16 partial, canonical [b][s1][s2][c]
constexpr size_t WS_NEED = (size_t)OFF_PW * 4 + (size_t)8 * 256 * 256 * 64 * 2;

// LDS geometry: rows of 256 col-slots, 16B per col, +16B pad per 8 cols.
constexpr int P   = 4624;          // row pitch bytes
constexpr int XFO = 8 * P;         // region B (Yt) after region A (staging/XfB)
constexpr int LDS_BYTES = 16 * P;  // 73984 B

__device__ __host__ inline int cadr(int c) { return c * 16 + (c >> 3) * 16; }

// ---- merged init: DFT/iDFT A-frag tables + both mix A2 tables ----
__global__ void k_init_all(const float* __restrict__ k0r, const float* __restrict__ k0i,
                           const float* __restrict__ k1r, const float* __restrict__ ki1,
                           float* __restrict__ ws) {
  const int bid = blockIdx.x;
  if (bid < 128) {
    int t = bid * 256 + threadIdx.x;  // 0..32767
    f16* fwdF = (f16*)(ws + OFF_FWDF);
    f16* invF = (f16*)(ws + OFF_INVF);
    if (t < 16384) {
      int e = t & 7, lane = (t >> 3) & 63, mtkk = t >> 9;
      int mt = mtkk & 1, kk = mtkk >> 1;
      int mc = mt * 32 + (lane & 31);
      int x = kk * 16 + 8 * (lane >> 5) + e;
      int r = mc >> 1;
      float ang = (float)((r * x) & 255) * (3.14159265358979323846f / 128.0f);
      float v = (mc & 1) ? -sinf(ang) : cosf(ang);
      fwdF[t] = (f16)v;
    } else {
      int t2 = t - 16384;
      int e = t2 & 7, lane = (t2 >> 3) & 63, mtg = (t2 >> 9) & 7, kk = t2 >> 12;
      int u = mtg * 32 + (lane & 31);
      int mcv = kk * 16 + 8 * (lane >> 5) + e;
      int r = mcv >> 1;
      float wgt = (r == 0) ? 1.0f : 2.0f;
      float ang = (float)((r * u) & 255) * (3.14159265358979323846f / 128.0f);
      float v = (mcv & 1) ? -wgt * sinf(ang) : wgt * cosf(ang);
      invF[t2] = (f16)(v * (1.0f / 256.0f));
    }
    return;
  }
  const int db = bid - 128;
  const float* kr = (db < 2048) ? k0r : k1r;
  const float* ki = (db < 2048) ? k0i : ki1;
  f16* A2 = (f16*)(ws + OFF_A2) + ((db < 2048) ? 0 : 524288);
  int t = (db & 2047) * 256 + threadIdx.x;  // 0..524287
  int e = t & 7, l = (t >> 3) & 63, kk = (t >> 9) & 7, mt = (t >> 12) & 3, r = t >> 14;
  int m = mt * 32 + (l & 31);
  int kreal = kk * 16 + 8 * (l >> 5) + e;
  int i = m >> 1, imo = m & 1, j = kreal >> 1, imi = kreal & 1;
  int src = (r * 64 + i) * 64 + j;
  float v = (imi == 0) ? ((imo == 0) ? kr[src] : ki[src])
                       : ((imo == 0) ? -ki[src] : kr[src]);
  A2[t] = (f16)v;
}

// ---- main fused kernel ----
// MODE 0: DIM0 -> out f32      MODE 1: DIM1, out += (f32 RMW)
// MODE 2: DIM0 -> pw f16 (canonical layout, lane-contiguous stores)
// MODE 3: DIM1, out = a4 + pw  (pw scalar-prefetched early)
template <int MODE>
__launch_bounds__(512, 2)
__global__ void k_dim(const float* __restrict__ X, const float* __restrict__ ws,
                      float* __restrict__ out, f16* __restrict__ pw) {
  constexpr int DIM = (MODE == 0 || MODE == 2) ? 0 : 1;
  __shared__ char sm[LDS_BYTES] __attribute__((aligned(16)));

  const int tid = threadIdx.x;
  const int l = tid & 63, w = tid >> 6;
  const int g2 = l >> 5, l31 = l & 31;
  const int n0 = w * 32;                   // wave's 32-col window
  // pass-2 runs in reversed logical order for L3 temporal locality
  const int bid = (DIM == 1) ? (int)(gridDim.x - 1 - blockIdx.x) : (int)blockIdx.x;
  const int b = bid >> 6;
  const int t4 = (bid & 63) * 4;           // first slab
  const size_t bbase = (size_t)b * (S * S * C);
  const f16* fwdF = (const f16*)(ws + OFF_FWDF);
  const f16* invF = (const f16*)(ws + OFF_INVF);
  const f16* A2 = (const f16*)(ws + OFF_A2) + (DIM == 0 ? 0 : 524288);

  // epilogue lane geometry (needed early for prefetch)
  const int colg = n0 + l31;
  const int pp = colg >> 6, jj = colg & 63;
  f16 pf0[64], pf1[64];                    // MODE 3 pw prefetch (h=0 / h=1)

  auto gofs = [&](int u, int c) -> size_t {
    if (DIM == 0)
      return bbase + (size_t)u * (S * C) + (size_t)(t4 + (c >> 6)) * C + (c & 63);
    else
      return bbase + (size_t)(t4 + (c >> 6)) * (S * C) + (size_t)u * C + (c & 63);
  };

  // staging assignment: wave -> (ug = w>>1 of 4 u-subrows, half = w&1 of col range)
  const int ug = w >> 1;
  const int c1 = (w & 1) * 128 + l;
  const int c2 = c1 + 64;

  float r1[8], r2[8];
  auto stage_load = [&](int u0) {
#pragma unroll
    for (int j = 0; j < 8; ++j) r1[j] = X[gofs(u0 + ug * 8 + j, c1)];
#pragma unroll
    for (int j = 0; j < 8; ++j) r2[j] = X[gofs(u0 + ug * 8 + j, c2)];
  };
  auto stage_write = [&](int buf) {
    f16x8 v1, v2;
#pragma unroll
    for (int j = 0; j < 8; ++j) { v1[j] = (f16)r1[j]; v2[j] = (f16)r2[j]; }
    char* base = sm + buf * (4 * P) + ug * P;
    *(f16x8*)(base + cadr(c1)) = v1;
    *(f16x8*)(base + cadr(c2)) = v2;
  };

  // ---------------- Phase 1: truncated DFT via MFMA ----------------
  f32x16 acc0, acc1;
#pragma unroll
  for (int q = 0; q < 16; ++q) { acc0[q] = 0.f; acc1[q] = 0.f; }

  stage_load(0);
  stage_write(0);
  __syncthreads();

  for (int ch = 0; ch < 8; ++ch) {
    if (ch < 7) stage_load((ch + 1) * 32);
    const char* bbuf = sm + (ch & 1) * (4 * P);
#pragma unroll
    for (int ks = 0; ks < 2; ++ks) {
      const int kk = ch * 2 + ks;
      f16x8 bf = *(const f16x8*)(bbuf + (ks * 2 + g2) * P + cadr(n0 + l31));
      f16x8 a0 = *(const f16x8*)(fwdF + ((size_t)(kk * 2 + 0) * 64 + l) * 8);
      f16x8 a1 = *(const f16x8*)(fwdF + ((size_t)(kk * 2 + 1) * 64 + l) * 8);
      acc0 = __builtin_amdgcn_mfma_f32_32x32x16_f16(a0, bf, acc0, 0, 0, 0);
      acc1 = __builtin_amdgcn_mfma_f32_32x32x16_f16(a1, bf, acc1, 0, 0, 0);
    }
    if (ch < 7) {
      stage_write((ch + 1) & 1);
      __syncthreads();
    }
  }
  __syncthreads();   // region A (staging) now safe to overwrite with XfB

  // ---------------- Phase 2: acc -> XfB directly (region A, B-frag order) ----
  {
    const int col = n0 + l31;
    const int p = col >> 6, j = col & 63;
    const int kk = j >> 3, g2p = (j >> 2) & 1, js = j & 3;
#pragma unroll
    for (int pr = 0; pr < 16; ++pr) {
      const int q = (pr & 7) >> 1, hf = pr & 1;
      const int r = 2 * g2 + 4 * q + hf + (pr >> 3) * 16;
      const int reg = 4 * q + 2 * hf;
      const float v0 = (pr < 8) ? acc0[reg] : acc1[reg];
      const float v1 = (pr < 8) ? acc0[reg + 1] : acc1[reg + 1];
      f16x2 v2 = {(f16)v0, (f16)v1};
      const int W = (r * 16 + kk * 2 + g2p) * 4 + p;
      *(f16x2*)(sm + W * 16 + (W >> 3) * 16 + js * 4) = v2;
    }
  }
  __syncthreads();

  // ---- MODE 3: issue h=0 pw prefetch (hidden under all of phase 3) ----
  // canonical address: pw[bbase + s1*16384 + s2*64 + c], s1 = t4+pp, s2 = u
  if constexpr (MODE == 3) {
    const f16* pwb = pw + bbase + (size_t)(t4 + pp) * (S * C) + jj;
#pragma unroll
    for (int mt = 0; mt < 4; ++mt)
#pragma unroll
      for (int reg = 0; reg < 16; ++reg) {
        const int u = mt * 32 + (reg & 3) + 8 * (reg >> 2) + 4 * g2;
        pf0[mt * 16 + reg] = pwb[(size_t)u * C];
      }
  }

  // ---------------- Phase 3: complex channel mix via MFMA ----------------
  {
    const int colsel = l31 & 3;
#pragma unroll 1
    for (int rq = 0; rq < 4; ++rq) {
      const int r = w * 4 + rq;
      f16x8 bfr[8];
#pragma unroll
      for (int kk = 0; kk < 8; ++kk) {
        const int W = (r * 16 + kk * 2 + g2) * 4 + colsel;
        bfr[kk] = *(const f16x8*)(sm + W * 16 + (W >> 3) * 16);
      }
      char* yb = sm + XFO + w * P;            // Yt row g3 = r>>2 = w
      const int ebyte = rq * 4;
#pragma unroll 1
      for (int mt = 0; mt < 4; ++mt) {
        f32x16 acc;
#pragma unroll
        for (int q = 0; q < 16; ++q) acc[q] = 0.f;
#pragma unroll
        for (int kk = 0; kk < 8; ++kk) {
          f16x8 af = *(const f16x8*)(A2 + ((size_t)((r * 4 + mt) * 8 + kk) * 64 + l) * 8);
          acc = __builtin_amdgcn_mfma_f32_32x32x16_f16(af, bfr[kk], acc, 0, 0, 0);
        }
        if (l31 < 4) {
#pragma unroll
          for (int t2 = 0; t2 < 8; ++t2) {
            int reg = t2 * 2;
            int rowin = (reg & 3) + 8 * (reg >> 2) + 4 * g2;   // even
            int i = (mt * 32 + rowin) >> 1;
            f16x2 v2 = {(f16)acc[reg], (f16)acc[reg + 1]};
            *(f16x2*)(yb + cadr(l31 * 64 + i) + ebyte) = v2;
          }
        }
      }
    }
  }
  __syncthreads();

  // ---- MODE 3: issue h=1 pw prefetch (hidden under bf4 loads + h=0 tiles) ----
  if constexpr (MODE == 3) {
    const f16* pwb = pw + bbase + (size_t)(t4 + pp) * (S * C) + jj;
#pragma unroll
    for (int mt = 0; mt < 4; ++mt)
#pragma unroll
      for (int reg = 0; reg < 16; ++reg) {
        const int u = 128 + mt * 32 + (reg & 3) + 8 * (reg >> 2) + 4 * g2;
        pf1[mt * 16 + reg] = pwb[(size_t)u * C];
      }
  }

  // ---------------- Phase 4: iDFT via MFMA -> direct fragment stores ----
  f16x8 bf4[4];
#pragma unroll
  for (int kk = 0; kk < 4; ++kk)
    bf4[kk] = *(const f16x8*)(sm + XFO + (kk * 2 + g2) * P + cadr(colg));

#pragma unroll
  for (int h = 0; h < 2; ++h) {
#pragma unroll
    for (int mt = 0; mt < 4; ++mt) {
      f32x16 a4;
#pragma unroll
      for (int q = 0; q < 16; ++q) a4[q] = 0.f;

#pragma unroll
      for (int kk = 0; kk < 4; ++kk) {
        f16x8 A = *(const f16x8*)(invF + ((size_t)(kk * 8 + h * 4 + mt) * 64 + l) * 8);
        a4 = __builtin_amdgcn_mfma_f32_32x32x16_f16(A, bf4[kk], a4, 0, 0, 0);
      }

      const int u0 = (h * 4 + mt) * 32;
#pragma unroll
      for (int reg = 0; reg < 16; ++reg) {
        const int u = u0 + (reg & 3) + 8 * (reg >> 2) + 4 * g2;
        if constexpr (MODE == 2) {
          // canonical pw: lane-contiguous 2B stores (dense 64B segments)
          size_t g = bbase + (size_t)u * (S * C) + (size_t)(t4 + pp) * C + jj;
          pw[g] = (f16)a4[reg];
        } else if constexpr (MODE == 3) {
          size_t g = bbase + (size_t)(t4 + pp) * (S * C) + (size_t)u * C + jj;
          const f16 pv = (h == 0) ? pf0[mt * 16 + reg] : pf1[mt * 16 + reg];
          out[g] = a4[reg] + (float)pv;
        } else {
          size_t g = (DIM == 0)
                         ? bbase + (size_t)u * (S * C) + (size_t)(t4 + pp) * C + jj
                         : bbase + (size_t)(t4 + pp) * (S * C) + (size_t)u * C + jj;
          if constexpr (MODE == 0) out[g] = a4[reg];
          else                     out[g] += a4[reg];
        }
      }
    }
  }
}

}  // namespace

extern "C" void kernel_launch(void* const* d_in, const int* in_sizes, int n_in,
                              void* d_out, int out_size, void* d_ws, size_t ws_size,
                              hipStream_t stream) {
  (void)in_sizes; (void)n_in; (void)out_size;
  const float* X   = (const float*)d_in[0];
  const float* k0r = (const float*)d_in[1];
  const float* k0i = (const float*)d_in[2];
  const float* k1r = (const float*)d_in[3];
  const float* k1i = (const float*)d_in[4];
  float* out = (float*)d_out;
  float* ws  = (float*)d_ws;
  f16* pw = (f16*)(ws + OFF_PW);

  k_init_all<<<4224, 256, 0, stream>>>(k0r, k0i, k1r, k1i, ws);
  if (ws_size >= WS_NEED) {
    k_dim<2><<<512, 512, 0, stream>>>(X, ws, out, pw);   // dim0 -> f16 partial
    k_dim<3><<<512, 512, 0, stream>>>(X, ws, out, pw);   // dim1 + partial -> out
  } else {
    k_dim<0><<<512, 512, 0, stream>>>(X, ws, out, nullptr);
    k_dim<1><<<512, 512, 0, stream>>>(X, ws, out, nullptr);
  }
}

// Round 14
// 164.446 us; speedup vs baseline: 1.1248x; 1.1248x over previous
//
#include <hip/hip_runtime.h>

// FactorizedSpectralConv: B=8, S1=S2=256, C=64, M1=M2=32.
// Fused per-dim kernels: truncated DFT (MFMA f16) -> complex mix (MFMA f16)
// -> iDFT (MFMA f16) -> direct fragment stores.
//
// R14 = R11 (best: 149.5us) + MODE-3 epilogue depth-1 software pipeline:
//   rolled ht loop (unroll 1 -- R12/R13 showed full unroll of phase 4 costs
//   ~2x on the epilogue), ping-pong named f16x8 vectors for pw prefetch
//   (no arrays -> no scratch), tile t+1's pw loads issued at tile t's top.
// R12 lesson: producer stores must stay lane-contiguous (canonical pw).
// R13 lesson: phase-4 must stay ROLLED; full unroll = +47us on k2.
//
// MFMA mapping discipline: logical k index f(g2,e) = 8*g2 + e used for BOTH
// A (init-built tables) and B (LDS staging layout). C/D layout:
// col = lane&31, row = (reg&3) + 8*(reg>>2) + 4*(lane>>5)  [HW-verified].
// Lessons: R3-R5 write-amp was register spills (keep VGPR budget >= need).

namespace {

constexpr int S = 256, C = 64;

typedef _Float16 f16;
typedef _Float16 f16x2 __attribute__((ext_vector_type(2)));
typedef _Float16 f16x4 __attribute__((ext_vector_type(4)));
typedef _Float16 f16x8 __attribute__((ext_vector_type(8)));
typedef float f32x16 __attribute__((ext_vector_type(16)));

// ws layout (float offsets)
constexpr int OFF_FWDF = 0;       // fwd A-frag table: 16384 f16 (8192 fl)
constexpr int OFF_INVF = 8192;    // inv A-frag table: 16384 f16 (8192 fl)
constexpr int OFF_A2   = 16384;   // mix A-frag tables: 2 dims x 524288 f16
constexpr int OFF_PW   = 540672;  // f16 partial, canonical [b][s1][s2][c]
constexpr size_t WS_NEED = (size_t)OFF_PW * 4 + (size_t)8 * 256 * 256 * 64 * 2;

// LDS geometry: rows of 256 col-slots, 16B per col, +16B pad per 8 cols.
constexpr int P   = 4624;          // row pitch bytes
constexpr int XFO = 8 * P;         // region B (Yt) after region A (staging/XfB)
constexpr int LDS_BYTES = 16 * P;  // 73984 B

__device__ __host__ inline int cadr(int c) { return c * 16 + (c >> 3) * 16; }

// ---- merged init: DFT/iDFT A-frag tables + both mix A2 tables ----
__global__ void k_init_all(const float* __restrict__ k0r, const float* __restrict__ k0i,
                           const float* __restrict__ k1r, const float* __restrict__ ki1,
                           float* __restrict__ ws) {
  const int bid = blockIdx.x;
  if (bid < 128) {
    int t = bid * 256 + threadIdx.x;  // 0..32767
    f16* fwdF = (f16*)(ws + OFF_FWDF);
    f16* invF = (f16*)(ws + OFF_INVF);
    if (t < 16384) {
      int e = t & 7, lane = (t >> 3) & 63, mtkk = t >> 9;
      int mt = mtkk & 1, kk = mtkk >> 1;
      int mc = mt * 32 + (lane & 31);
      int x = kk * 16 + 8 * (lane >> 5) + e;
      int r = mc >> 1;
      float ang = (float)((r * x) & 255) * (3.14159265358979323846f / 128.0f);
      float v = (mc & 1) ? -sinf(ang) : cosf(ang);
      fwdF[t] = (f16)v;
    } else {
      int t2 = t - 16384;
      int e = t2 & 7, lane = (t2 >> 3) & 63, mtg = (t2 >> 9) & 7, kk = t2 >> 12;
      int u = mtg * 32 + (lane & 31);
      int mcv = kk * 16 + 8 * (lane >> 5) + e;
      int r = mcv >> 1;
      float wgt = (r == 0) ? 1.0f : 2.0f;
      float ang = (float)((r * u) & 255) * (3.14159265358979323846f / 128.0f);
      float v = (mcv & 1) ? -wgt * sinf(ang) : wgt * cosf(ang);
      invF[t2] = (f16)(v * (1.0f / 256.0f));
    }
    return;
  }
  const int db = bid - 128;
  const float* kr = (db < 2048) ? k0r : k1r;
  const float* ki = (db < 2048) ? k0i : ki1;
  f16* A2 = (f16*)(ws + OFF_A2) + ((db < 2048) ? 0 : 524288);
  int t = (db & 2047) * 256 + threadIdx.x;  // 0..524287
  int e = t & 7, l = (t >> 3) & 63, kk = (t >> 9) & 7, mt = (t >> 12) & 3, r = t >> 14;
  int m = mt * 32 + (l & 31);
  int kreal = kk * 16 + 8 * (l >> 5) + e;
  int i = m >> 1, imo = m & 1, j = kreal >> 1, imi = kreal & 1;
  int src = (r * 64 + i) * 64 + j;
  float v = (imi == 0) ? ((imo == 0) ? kr[src] : ki[src])
                       : ((imo == 0) ? -ki[src] : kr[src]);
  A2[t] = (f16)v;
}

// ---- main fused kernel ----
// MODE 0: DIM0 -> out f32      MODE 1: DIM1, out += (f32 RMW)
// MODE 2: DIM0 -> pw f16 (canonical layout, lane-contiguous stores)
// MODE 3: DIM1, out = a4 + pw  (rolled depth-1 pipelined pw prefetch)
template <int MODE>
__launch_bounds__(512, 2)
__global__ void k_dim(const float* __restrict__ X, const float* __restrict__ ws,
                      float* __restrict__ out, f16* __restrict__ pw) {
  constexpr int DIM = (MODE == 0 || MODE == 2) ? 0 : 1;
  __shared__ char sm[LDS_BYTES] __attribute__((aligned(16)));

  const int tid = threadIdx.x;
  const int l = tid & 63, w = tid >> 6;
  const int g2 = l >> 5, l31 = l & 31;
  const int n0 = w * 32;                   // wave's 32-col window
  // pass-2 runs in reversed logical order for L3 temporal locality
  const int bid = (DIM == 1) ? (int)(gridDim.x - 1 - blockIdx.x) : (int)blockIdx.x;
  const int b = bid >> 6;
  const int t4 = (bid & 63) * 4;           // first slab
  const size_t bbase = (size_t)b * (S * S * C);
  const f16* fwdF = (const f16*)(ws + OFF_FWDF);
  const f16* invF = (const f16*)(ws + OFF_INVF);
  const f16* A2 = (const f16*)(ws + OFF_A2) + (DIM == 0 ? 0 : 524288);

  const int colg = n0 + l31;
  const int pp = colg >> 6, jj = colg & 63;

  auto gofs = [&](int u, int c) -> size_t {
    if (DIM == 0)
      return bbase + (size_t)u * (S * C) + (size_t)(t4 + (c >> 6)) * C + (c & 63);
    else
      return bbase + (size_t)(t4 + (c >> 6)) * (S * C) + (size_t)u * C + (c & 63);
  };

  // staging assignment: wave -> (ug = w>>1 of 4 u-subrows, half = w&1 of col range)
  const int ug = w >> 1;
  const int c1 = (w & 1) * 128 + l;
  const int c2 = c1 + 64;

  float r1[8], r2[8];
  auto stage_load = [&](int u0) {
#pragma unroll
    for (int j = 0; j < 8; ++j) r1[j] = X[gofs(u0 + ug * 8 + j, c1)];
#pragma unroll
    for (int j = 0; j < 8; ++j) r2[j] = X[gofs(u0 + ug * 8 + j, c2)];
  };
  auto stage_write = [&](int buf) {
    f16x8 v1, v2;
#pragma unroll
    for (int j = 0; j < 8; ++j) { v1[j] = (f16)r1[j]; v2[j] = (f16)r2[j]; }
    char* base = sm + buf * (4 * P) + ug * P;
    *(f16x8*)(base + cadr(c1)) = v1;
    *(f16x8*)(base + cadr(c2)) = v2;
  };

  // ---------------- Phase 1: truncated DFT via MFMA ----------------
  f32x16 acc0, acc1;
#pragma unroll
  for (int q = 0; q < 16; ++q) { acc0[q] = 0.f; acc1[q] = 0.f; }

  stage_load(0);
  stage_write(0);
  __syncthreads();

  for (int ch = 0; ch < 8; ++ch) {
    if (ch < 7) stage_load((ch + 1) * 32);
    const char* bbuf = sm + (ch & 1) * (4 * P);
#pragma unroll
    for (int ks = 0; ks < 2; ++ks) {
      const int kk = ch * 2 + ks;
      f16x8 bf = *(const f16x8*)(bbuf + (ks * 2 + g2) * P + cadr(n0 + l31));
      f16x8 a0 = *(const f16x8*)(fwdF + ((size_t)(kk * 2 + 0) * 64 + l) * 8);
      f16x8 a1 = *(const f16x8*)(fwdF + ((size_t)(kk * 2 + 1) * 64 + l) * 8);
      acc0 = __builtin_amdgcn_mfma_f32_32x32x16_f16(a0, bf, acc0, 0, 0, 0);
      acc1 = __builtin_amdgcn_mfma_f32_32x32x16_f16(a1, bf, acc1, 0, 0, 0);
    }
    if (ch < 7) {
      stage_write((ch + 1) & 1);
      __syncthreads();
    }
  }
  __syncthreads();   // region A (staging) now safe to overwrite with XfB

  // ---------------- Phase 2: acc -> XfB directly (region A, B-frag order) ----
  {
    const int col = n0 + l31;
    const int p = col >> 6, j = col & 63;
    const int kk = j >> 3, g2p = (j >> 2) & 1, js = j & 3;
#pragma unroll
    for (int pr = 0; pr < 16; ++pr) {
      const int q = (pr & 7) >> 1, hf = pr & 1;
      const int r = 2 * g2 + 4 * q + hf + (pr >> 3) * 16;
      const int reg = 4 * q + 2 * hf;
      const float v0 = (pr < 8) ? acc0[reg] : acc1[reg];
      const float v1 = (pr < 8) ? acc0[reg + 1] : acc1[reg + 1];
      f16x2 v2 = {(f16)v0, (f16)v1};
      const int W = (r * 16 + kk * 2 + g2p) * 4 + p;
      *(f16x2*)(sm + W * 16 + (W >> 3) * 16 + js * 4) = v2;
    }
  }
  __syncthreads();

  // ---------------- Phase 3: complex channel mix via MFMA ----------------
  {
    const int colsel = l31 & 3;
#pragma unroll 1
    for (int rq = 0; rq < 4; ++rq) {
      const int r = w * 4 + rq;
      f16x8 bfr[8];
#pragma unroll
      for (int kk = 0; kk < 8; ++kk) {
        const int W = (r * 16 + kk * 2 + g2) * 4 + colsel;
        bfr[kk] = *(const f16x8*)(sm + W * 16 + (W >> 3) * 16);
      }
      char* yb = sm + XFO + w * P;            // Yt row g3 = r>>2 = w
      const int ebyte = rq * 4;
#pragma unroll 1
      for (int mt = 0; mt < 4; ++mt) {
        f32x16 acc;
#pragma unroll
        for (int q = 0; q < 16; ++q) acc[q] = 0.f;
#pragma unroll
        for (int kk = 0; kk < 8; ++kk) {
          f16x8 af = *(const f16x8*)(A2 + ((size_t)((r * 4 + mt) * 8 + kk) * 64 + l) * 8);
          acc = __builtin_amdgcn_mfma_f32_32x32x16_f16(af, bfr[kk], acc, 0, 0, 0);
        }
        if (l31 < 4) {
#pragma unroll
          for (int t2 = 0; t2 < 8; ++t2) {
            int reg = t2 * 2;
            int rowin = (reg & 3) + 8 * (reg >> 2) + 4 * g2;   // even
            int i = (mt * 32 + rowin) >> 1;
            f16x2 v2 = {(f16)acc[reg], (f16)acc[reg + 1]};
            *(f16x2*)(yb + cadr(l31 * 64 + i) + ebyte) = v2;
          }
        }
      }
    }
  }
  __syncthreads();

  // ---------------- Phase 4: iDFT via MFMA -> direct fragment stores ----
  f16x8 bf4[4];
#pragma unroll
  for (int kk = 0; kk < 4; ++kk)
    bf4[kk] = *(const f16x8*)(sm + XFO + (kk * 2 + g2) * P + cadr(colg));

  if constexpr (MODE == 3) {
    // Rolled depth-1 pipelined epilogue: ping-pong named f16x8 pairs (cA/cB
    // vs nA/nB) hold tile pw values; tile t+1's 16 scalar pw loads issue at
    // tile t's top and are consumed one body later.
    const f16* pwb = pw + bbase + (size_t)(t4 + pp) * (S * C) + jj;
    f16x8 cA, cB, nA, nB;
#pragma unroll
    for (int reg = 0; reg < 16; ++reg) {
      const int u = (reg & 3) + 8 * (reg >> 2) + 4 * g2;
      f16 v = pwb[(size_t)u * C];
      if (reg < 8) cA[reg & 7] = v; else cB[reg & 7] = v;
    }
#pragma unroll 1
    for (int htp = 0; htp < 4; ++htp) {
      // ---- body A: tile ht = 2*htp (uses cA/cB), prefetch 2*htp+1 -> nA/nB
      {
        const int ht = 2 * htp;
#pragma unroll
        for (int reg = 0; reg < 16; ++reg) {
          const int u = (ht + 1) * 32 + (reg & 3) + 8 * (reg >> 2) + 4 * g2;
          f16 v = pwb[(size_t)u * C];
          if (reg < 8) nA[reg & 7] = v; else nB[reg & 7] = v;
        }
        f32x16 a4;
#pragma unroll
        for (int q = 0; q < 16; ++q) a4[q] = 0.f;
#pragma unroll
        for (int kk = 0; kk < 4; ++kk) {
          f16x8 A = *(const f16x8*)(invF + ((size_t)(kk * 8 + ht) * 64 + l) * 8);
          a4 = __builtin_amdgcn_mfma_f32_32x32x16_f16(A, bf4[kk], a4, 0, 0, 0);
        }
#pragma unroll
        for (int reg = 0; reg < 16; ++reg) {
          const int u = ht * 32 + (reg & 3) + 8 * (reg >> 2) + 4 * g2;
          size_t g = bbase + (size_t)(t4 + pp) * (S * C) + (size_t)u * C + jj;
          f16 pv = (reg < 8) ? cA[reg & 7] : cB[reg & 7];
          out[g] = a4[reg] + (float)pv;
        }
      }
      // ---- body B: tile ht = 2*htp+1 (uses nA/nB), prefetch 2*htp+2 -> cA/cB
      {
        const int ht = 2 * htp + 1;
        if (htp < 3) {
#pragma unroll
          for (int reg = 0; reg < 16; ++reg) {
            const int u = (ht + 1) * 32 + (reg & 3) + 8 * (reg >> 2) + 4 * g2;
            f16 v = pwb[(size_t)u * C];
            if (reg < 8) cA[reg & 7] = v; else cB[reg & 7] = v;
          }
        }
        f32x16 a4;
#pragma unroll
        for (int q = 0; q < 16; ++q) a4[q] = 0.f;
#pragma unroll
        for (int kk = 0; kk < 4; ++kk) {
          f16x8 A = *(const f16x8*)(invF + ((size_t)(kk * 8 + ht) * 64 + l) * 8);
          a4 = __builtin_amdgcn_mfma_f32_32x32x16_f16(A, bf4[kk], a4, 0, 0, 0);
        }
#pragma unroll
        for (int reg = 0; reg < 16; ++reg) {
          const int u = ht * 32 + (reg & 3) + 8 * (reg >> 2) + 4 * g2;
          size_t g = bbase + (size_t)(t4 + pp) * (S * C) + (size_t)u * C + jj;
          f16 pv = (reg < 8) ? nA[reg & 7] : nB[reg & 7];
          out[g] = a4[reg] + (float)pv;
        }
      }
    }
  } else {
    // R11 epilogue (rolled) for MODE 0/1/2
#pragma unroll 1
    for (int h = 0; h < 2; ++h) {
#pragma unroll 1
      for (int mt = 0; mt < 4; ++mt) {
        f32x16 a4;
#pragma unroll
        for (int q = 0; q < 16; ++q) a4[q] = 0.f;

#pragma unroll
        for (int kk = 0; kk < 4; ++kk) {
          f16x8 A = *(const f16x8*)(invF + ((size_t)(kk * 8 + h * 4 + mt) * 64 + l) * 8);
          a4 = __builtin_amdgcn_mfma_f32_32x32x16_f16(A, bf4[kk], a4, 0, 0, 0);
        }

        const int u0 = (h * 4 + mt) * 32;
#pragma unroll
        for (int reg = 0; reg < 16; ++reg) {
          const int u = u0 + (reg & 3) + 8 * (reg >> 2) + 4 * g2;
          if constexpr (MODE == 2) {
            size_t g = bbase + (size_t)u * (S * C) + (size_t)(t4 + pp) * C + jj;
            pw[g] = (f16)a4[reg];
          } else {
            size_t g = (DIM == 0)
                           ? bbase + (size_t)u * (S * C) + (size_t)(t4 + pp) * C + jj
                           : bbase + (size_t)(t4 + pp) * (S * C) + (size_t)u * C + jj;
            if constexpr (MODE == 0) out[g] = a4[reg];
            else                     out[g] += a4[reg];
          }
        }
      }
    }
  }
}

}  // namespace

extern "C" void kernel_launch(void* const* d_in, const int* in_sizes, int n_in,
                              void* d_out, int out_size, void* d_ws, size_t ws_size,
                              hipStream_t stream) {
  (void)in_sizes; (void)n_in; (void)out_size;
  const float* X   = (const float*)d_in[0];
  const float* k0r = (const float*)d_in[1];
  const float* k0i = (const float*)d_in[2];
  const float* k1r = (const float*)d_in[3];
  const float* k1i = (const float*)d_in[4];
  float* out = (float*)d_out;
  float* ws  = (float*)d_ws;
  f16* pw = (f16*)(ws + OFF_PW);

  k_init_all<<<4224, 256, 0, stream>>>(k0r, k0i, k1r, k1i, ws);
  if (ws_size >= WS_NEED) {
    k_dim<2><<<512, 512, 0, stream>>>(X, ws, out, pw);   // dim0 -> f16 partial
    k_dim<3><<<512, 512, 0, stream>>>(X, ws, out, pw);   // dim1 + partial -> out
  } else {
    k_dim<0><<<512, 512, 0, stream>>>(X, ws, out, nullptr);
    k_dim<1><<<512, 512, 0, stream>>>(X, ws, out, nullptr);
  }
}

// Round 15
// 151.222 us; speedup vs baseline: 1.2231x; 1.0875x over previous
//
#include <hip/hip_runtime.h>

// FactorizedSpectralConv: B=8, S1=S2=256, C=64, M1=M2=32.
// Fused per-dim kernels: truncated DFT (MFMA f16) -> complex mix (MFMA f16)
// -> iDFT (MFMA f16) -> direct fragment stores.
//
// R15 = R11 (best: 149.5us) + Yt-overlay LDS cut (74KB -> 36.1KB):
//   Yt(r) (1KB) is written into mode r's XfB slot (1152B @ 1152*r) right
//   after wave w=r>>2 consumes that slot into bfr regs -- WAR-safe within
//   wave, slot untouched by other waves in phase 3, existing barriers cover
//   phases 2->3->4. Phase 4 gathers its B-frags as 4 x u32 per kk.
//   2 blocks/CU (LDS-bound) -> 3 blocks/CU (VGPR-bound at ~76) for better
//   cross-block phase overlap. No other changes.
// R12 lesson: producer stores must stay lane-contiguous (canonical pw).
// R13/R14 lesson: epilogue must stay ROLLED and SIMPLE (inline pw read).
//
// MFMA mapping discipline: logical k index f(g2,e) = 8*g2 + e used for BOTH
// A (init-built tables) and B (LDS staging layout). C/D layout:
// col = lane&31, row = (reg&3) + 8*(reg>>2) + 4*(lane>>5)  [HW-verified].
// Lessons: R3-R5 write-amp was register spills (keep VGPR budget >= need).

namespace {

constexpr int S = 256, C = 64;

typedef _Float16 f16;
typedef _Float16 f16x2 __attribute__((ext_vector_type(2)));
typedef _Float16 f16x4 __attribute__((ext_vector_type(4)));
typedef _Float16 f16x8 __attribute__((ext_vector_type(8)));
typedef float f32x16 __attribute__((ext_vector_type(16)));
typedef unsigned int u32;

// ws layout (float offsets)
constexpr int OFF_FWDF = 0;       // fwd A-frag table: 16384 f16 (8192 fl)
constexpr int OFF_INVF = 8192;    // inv A-frag table: 16384 f16 (8192 fl)
constexpr int OFF_A2   = 16384;   // mix A-frag tables: 2 dims x 524288 f16
constexpr int OFF_PW   = 540672;  // f16 partial, canonical [b][s1][s2][c]
constexpr size_t WS_NEED = (size_t)OFF_PW * 4 + (size_t)8 * 256 * 256 * 64 * 2;

// LDS geometry: rows of 256 col-slots, 16B per col, +16B pad per 8 cols.
constexpr int P   = 4624;          // row pitch bytes (staging region)
constexpr int LDS_BYTES = 8 * P;   // 36992 B (region A only; Yt overlays XfB)

__device__ __host__ inline int cadr(int c) { return c * 16 + (c >> 3) * 16; }
// Yt slot address: mode r's 1KB lives inside XfB slot [1152r, 1152r+1152)
__device__ inline int yadr(int r, int c) { return 1152 * r + c * 4 + (c >> 5) * 16; }

// ---- merged init: DFT/iDFT A-frag tables + both mix A2 tables ----
__global__ void k_init_all(const float* __restrict__ k0r, const float* __restrict__ k0i,
                           const float* __restrict__ k1r, const float* __restrict__ ki1,
                           float* __restrict__ ws) {
  const int bid = blockIdx.x;
  if (bid < 128) {
    int t = bid * 256 + threadIdx.x;  // 0..32767
    f16* fwdF = (f16*)(ws + OFF_FWDF);
    f16* invF = (f16*)(ws + OFF_INVF);
    if (t < 16384) {
      int e = t & 7, lane = (t >> 3) & 63, mtkk = t >> 9;
      int mt = mtkk & 1, kk = mtkk >> 1;
      int mc = mt * 32 + (lane & 31);
      int x = kk * 16 + 8 * (lane >> 5) + e;
      int r = mc >> 1;
      float ang = (float)((r * x) & 255) * (3.14159265358979323846f / 128.0f);
      float v = (mc & 1) ? -sinf(ang) : cosf(ang);
      fwdF[t] = (f16)v;
    } else {
      int t2 = t - 16384;
      int e = t2 & 7, lane = (t2 >> 3) & 63, mtg = (t2 >> 9) & 7, kk = t2 >> 12;
      int u = mtg * 32 + (lane & 31);
      int mcv = kk * 16 + 8 * (lane >> 5) + e;
      int r = mcv >> 1;
      float wgt = (r == 0) ? 1.0f : 2.0f;
      float ang = (float)((r * u) & 255) * (3.14159265358979323846f / 128.0f);
      float v = (mcv & 1) ? -wgt * sinf(ang) : wgt * cosf(ang);
      invF[t2] = (f16)(v * (1.0f / 256.0f));
    }
    return;
  }
  const int db = bid - 128;
  const float* kr = (db < 2048) ? k0r : k1r;
  const float* ki = (db < 2048) ? k0i : ki1;
  f16* A2 = (f16*)(ws + OFF_A2) + ((db < 2048) ? 0 : 524288);
  int t = (db & 2047) * 256 + threadIdx.x;  // 0..524287
  int e = t & 7, l = (t >> 3) & 63, kk = (t >> 9) & 7, mt = (t >> 12) & 3, r = t >> 14;
  int m = mt * 32 + (l & 31);
  int kreal = kk * 16 + 8 * (l >> 5) + e;
  int i = m >> 1, imo = m & 1, j = kreal >> 1, imi = kreal & 1;
  int src = (r * 64 + i) * 64 + j;
  float v = (imi == 0) ? ((imo == 0) ? kr[src] : ki[src])
                       : ((imo == 0) ? -ki[src] : kr[src]);
  A2[t] = (f16)v;
}

// ---- main fused kernel ----
// MODE 0: DIM0 -> out f32      MODE 1: DIM1, out += (f32 RMW)
// MODE 2: DIM0 -> pw f16 (canonical layout, lane-contiguous stores)
// MODE 3: DIM1, out = a4 + pw  (inline pw read)
template <int MODE>
__launch_bounds__(512, 2)
__global__ void k_dim(const float* __restrict__ X, const float* __restrict__ ws,
                      float* __restrict__ out, f16* __restrict__ pw) {
  constexpr int DIM = (MODE == 0 || MODE == 2) ? 0 : 1;
  __shared__ char sm[LDS_BYTES] __attribute__((aligned(16)));

  const int tid = threadIdx.x;
  const int l = tid & 63, w = tid >> 6;
  const int g2 = l >> 5, l31 = l & 31;
  const int n0 = w * 32;                   // wave's 32-col window
  // pass-2 runs in reversed logical order for L3 temporal locality
  const int bid = (DIM == 1) ? (int)(gridDim.x - 1 - blockIdx.x) : (int)blockIdx.x;
  const int b = bid >> 6;
  const int t4 = (bid & 63) * 4;           // first slab
  const size_t bbase = (size_t)b * (S * S * C);
  const f16* fwdF = (const f16*)(ws + OFF_FWDF);
  const f16* invF = (const f16*)(ws + OFF_INVF);
  const f16* A2 = (const f16*)(ws + OFF_A2) + (DIM == 0 ? 0 : 524288);

  const int colg = n0 + l31;
  const int pp = colg >> 6, jj = colg & 63;

  auto gofs = [&](int u, int c) -> size_t {
    if (DIM == 0)
      return bbase + (size_t)u * (S * C) + (size_t)(t4 + (c >> 6)) * C + (c & 63);
    else
      return bbase + (size_t)(t4 + (c >> 6)) * (S * C) + (size_t)u * C + (c & 63);
  };

  // staging assignment: wave -> (ug = w>>1 of 4 u-subrows, half = w&1 of col range)
  const int ug = w >> 1;
  const int c1 = (w & 1) * 128 + l;
  const int c2 = c1 + 64;

  float r1[8], r2[8];
  auto stage_load = [&](int u0) {
#pragma unroll
    for (int j = 0; j < 8; ++j) r1[j] = X[gofs(u0 + ug * 8 + j, c1)];
#pragma unroll
    for (int j = 0; j < 8; ++j) r2[j] = X[gofs(u0 + ug * 8 + j, c2)];
  };
  auto stage_write = [&](int buf) {
    f16x8 v1, v2;
#pragma unroll
    for (int j = 0; j < 8; ++j) { v1[j] = (f16)r1[j]; v2[j] = (f16)r2[j]; }
    char* base = sm + buf * (4 * P) + ug * P;
    *(f16x8*)(base + cadr(c1)) = v1;
    *(f16x8*)(base + cadr(c2)) = v2;
  };

  // ---------------- Phase 1: truncated DFT via MFMA ----------------
  f32x16 acc0, acc1;
#pragma unroll
  for (int q = 0; q < 16; ++q) { acc0[q] = 0.f; acc1[q] = 0.f; }

  stage_load(0);
  stage_write(0);
  __syncthreads();

  for (int ch = 0; ch < 8; ++ch) {
    if (ch < 7) stage_load((ch + 1) * 32);
    const char* bbuf = sm + (ch & 1) * (4 * P);
#pragma unroll
    for (int ks = 0; ks < 2; ++ks) {
      const int kk = ch * 2 + ks;
      f16x8 bf = *(const f16x8*)(bbuf + (ks * 2 + g2) * P + cadr(n0 + l31));
      f16x8 a0 = *(const f16x8*)(fwdF + ((size_t)(kk * 2 + 0) * 64 + l) * 8);
      f16x8 a1 = *(const f16x8*)(fwdF + ((size_t)(kk * 2 + 1) * 64 + l) * 8);
      acc0 = __builtin_amdgcn_mfma_f32_32x32x16_f16(a0, bf, acc0, 0, 0, 0);
      acc1 = __builtin_amdgcn_mfma_f32_32x32x16_f16(a1, bf, acc1, 0, 0, 0);
    }
    if (ch < 7) {
      stage_write((ch + 1) & 1);
      __syncthreads();
    }
  }
  __syncthreads();   // staging dead; region now holds XfB

  // ---------------- Phase 2: acc -> XfB directly (B-frag order) ----------------
  {
    const int col = n0 + l31;
    const int p = col >> 6, j = col & 63;
    const int kk = j >> 3, g2p = (j >> 2) & 1, js = j & 3;
#pragma unroll
    for (int pr = 0; pr < 16; ++pr) {
      const int q = (pr & 7) >> 1, hf = pr & 1;
      const int r = 2 * g2 + 4 * q + hf + (pr >> 3) * 16;
      const int reg = 4 * q + 2 * hf;
      const float v0 = (pr < 8) ? acc0[reg] : acc1[reg];
      const float v1 = (pr < 8) ? acc0[reg + 1] : acc1[reg + 1];
      f16x2 v2 = {(f16)v0, (f16)v1};
      const int W = (r * 16 + kk * 2 + g2p) * 4 + p;
      *(f16x2*)(sm + W * 16 + (W >> 3) * 16 + js * 4) = v2;
    }
  }
  __syncthreads();

  // ---------------- Phase 3: complex channel mix via MFMA ----------------
  // Wave w: modes r = w*4 + rq. bfr (8 frags) loaded from XfB slot r, then
  // Yt(r) is written INTO slot r (now dead): yadr(r, slab*64 + i).
  {
    const int colsel = l31 & 3;
#pragma unroll 1
    for (int rq = 0; rq < 4; ++rq) {
      const int r = w * 4 + rq;
      f16x8 bfr[8];
#pragma unroll
      for (int kk = 0; kk < 8; ++kk) {
        const int W = (r * 16 + kk * 2 + g2) * 4 + colsel;
        bfr[kk] = *(const f16x8*)(sm + W * 16 + (W >> 3) * 16);
      }
#pragma unroll 1
      for (int mt = 0; mt < 4; ++mt) {
        f32x16 acc;
#pragma unroll
        for (int q = 0; q < 16; ++q) acc[q] = 0.f;
#pragma unroll
        for (int kk = 0; kk < 8; ++kk) {
          f16x8 af = *(const f16x8*)(A2 + ((size_t)((r * 4 + mt) * 8 + kk) * 64 + l) * 8);
          acc = __builtin_amdgcn_mfma_f32_32x32x16_f16(af, bfr[kk], acc, 0, 0, 0);
        }
        if (l31 < 4) {
#pragma unroll
          for (int t2 = 0; t2 < 8; ++t2) {
            int reg = t2 * 2;
            int rowin = (reg & 3) + 8 * (reg >> 2) + 4 * g2;   // even
            int i = (mt * 32 + rowin) >> 1;
            f16x2 v2 = {(f16)acc[reg], (f16)acc[reg + 1]};
            *(f16x2*)(sm + yadr(r, l31 * 64 + i)) = v2;
          }
        }
      }
    }
  }
  __syncthreads();

  // ---------------- Phase 4: iDFT via MFMA -> direct fragment stores ----
  // B-frag kk: element pair (2s, 2s+1) = Yt word of slot r0+s at col colg,
  // r0 = 8*kk + 4*g2  (mc = 16kk + 8g2 + 2s + im).
  f16x8 bf4[4];
  {
    const int cb = colg * 4 + (colg >> 5) * 16;
#pragma unroll
    for (int kk = 0; kk < 4; ++kk) {
      union { f16x8 h; u32 u[4]; } bb;
      const int r0 = 8 * kk + 4 * g2;
#pragma unroll
      for (int s = 0; s < 4; ++s)
        bb.u[s] = *(const u32*)(sm + 1152 * (r0 + s) + cb);
      bf4[kk] = bb.h;
    }
  }

#pragma unroll 1
  for (int h = 0; h < 2; ++h) {
#pragma unroll 1
    for (int mt = 0; mt < 4; ++mt) {
      f32x16 a4;
#pragma unroll
      for (int q = 0; q < 16; ++q) a4[q] = 0.f;

#pragma unroll
      for (int kk = 0; kk < 4; ++kk) {
        f16x8 A = *(const f16x8*)(invF + ((size_t)(kk * 8 + h * 4 + mt) * 64 + l) * 8);
        a4 = __builtin_amdgcn_mfma_f32_32x32x16_f16(A, bf4[kk], a4, 0, 0, 0);
      }

      const int u0 = (h * 4 + mt) * 32;
#pragma unroll
      for (int reg = 0; reg < 16; ++reg) {
        const int u = u0 + (reg & 3) + 8 * (reg >> 2) + 4 * g2;
        if constexpr (MODE == 2) {
          size_t g = bbase + (size_t)u * (S * C) + (size_t)(t4 + pp) * C + jj;
          pw[g] = (f16)a4[reg];
        } else if constexpr (MODE == 3) {
          size_t g = bbase + (size_t)(t4 + pp) * (S * C) + (size_t)u * C + jj;
          out[g] = a4[reg] + (float)pw[g];
        } else {
          size_t g = (DIM == 0)
                         ? bbase + (size_t)u * (S * C) + (size_t)(t4 + pp) * C + jj
                         : bbase + (size_t)(t4 + pp) * (S * C) + (size_t)u * C + jj;
          if constexpr (MODE == 0) out[g] = a4[reg];
          else                     out[g] += a4[reg];
        }
      }
    }
  }
}

}  // namespace

extern "C" void kernel_launch(void* const* d_in, const int* in_sizes, int n_in,
                              void* d_out, int out_size, void* d_ws, size_t ws_size,
                              hipStream_t stream) {
  (void)in_sizes; (void)n_in; (void)out_size;
  const float* X   = (const float*)d_in[0];
  const float* k0r = (const float*)d_in[1];
  const float* k0i = (const float*)d_in[2];
  const float* k1r = (const float*)d_in[3];
  const float* k1i = (const float*)d_in[4];
  float* out = (float*)d_out;
  float* ws  = (float*)d_ws;
  f16* pw = (f16*)(ws + OFF_PW);

  k_init_all<<<4224, 256, 0, stream>>>(k0r, k0i, k1r, k1i, ws);
  if (ws_size >= WS_NEED) {
    k_dim<2><<<512, 512, 0, stream>>>(X, ws, out, pw);   // dim0 -> f16 partial
    k_dim<3><<<512, 512, 0, stream>>>(X, ws, out, pw);   // dim1 + partial -> out
  } else {
    k_dim<0><<<512, 512, 0, stream>>>(X, ws, out, nullptr);
    k_dim<1><<<512, 512, 0, stream>>>(X, ws, out, nullptr);
  }
}